// Round 1
// baseline (474.770 us; speedup 1.0000x reference)
//
#include <hip/hip_runtime.h>

#define BB 4
#define CC 3
#define HH 512
#define WW 512
#define NSHIFT 81          // 9 x 9
#define IMG (HH * WW)
#define CHW (CC * HH * WW)
#define ROWS 8             // rows per block in k_sims

// ws layout: double sims[BB*NSHIFT] at byte 0; int best[BB*2] at byte 4096.

__global__ void k_init(double* __restrict__ sims) {
    int i = blockIdx.x * blockDim.x + threadIdx.x;
    if (i < BB * NSHIFT) sims[i] = 0.0;
}

// sim(b,sx,sy) = sum over c,i,j (both (i,j) and (i+sx,j+sy) in bounds) of
//               x[b,c,i,j] * x_ref[b,c,i+sx,j+sy]
__global__ __launch_bounds__(256) void k_sims(const float* __restrict__ xref,
                                              const float* __restrict__ x,
                                              double* __restrict__ sims) {
    const int blocksPerImage = HH / ROWS;            // 64
    int bid = blockIdx.x;
    int r0  = (bid % blocksPerImage) * ROWS;
    int bc  = bid / blocksPerImage;                  // 0 .. B*C-1
    int b   = bc / CC;
    const float* xp = x    + (size_t)bc * IMG;
    const float* rp = xref + (size_t)bc * IMG;
    int tid  = threadIdx.x;
    int lane = tid & 63;

    for (int sxi = 0; sxi < 9; ++sxi) {
        int sx = sxi - 4;
        double acc[9];
#pragma unroll
        for (int k = 0; k < 9; ++k) acc[k] = 0.0;

        for (int r = 0; r < ROWS; ++r) {
            int ip = r0 + r;         // row of x
            int ii = ip + sx;        // row of x_ref
            if (ii < 0 || ii >= HH) continue;
            const float* xrow = xp + ip * WW;
            const float* rrow = rp + ii * WW;
            for (int j = tid; j < WW; j += 256) {
                float xv = xrow[j];
#pragma unroll
                for (int syi = 0; syi < 9; ++syi) {
                    int jr = j + syi - 4;
                    if (jr >= 0 && jr < WW)
                        acc[syi] += (double)xv * (double)rrow[jr];
                }
            }
        }
        // wave-level reduce (64 lanes), then one atomic per wave per sy
#pragma unroll
        for (int k = 0; k < 9; ++k) {
            double v = acc[k];
            for (int off = 32; off; off >>= 1)
                v += __shfl_down(v, off, 64);
            if (lane == 0)
                atomicAdd(&sims[b * NSHIFT + sxi * 9 + k], v);
        }
    }
}

// One block (64 threads) per batch: argmax with first-index tie-break.
__global__ void k_argmax(const double* __restrict__ sims,
                         int* __restrict__ best,
                         float* __restrict__ outTail) {
    int b = blockIdx.x;
    int t = threadIdx.x;        // 0..63
    double bv = -1.0e300;
    int bi = NSHIFT;            // sentinel larger than any real index
    for (int s = t; s < NSHIFT; s += 64) {
        double v = sims[b * NSHIFT + s];
        if (v > bv || (v == bv && s < bi)) { bv = v; bi = s; }
    }
    for (int off = 32; off; off >>= 1) {
        double ov = __shfl_down(bv, off, 64);
        int    oi = __shfl_down(bi, off, 64);
        if (ov > bv || (ov == bv && oi < bi)) { bv = ov; bi = oi; }
    }
    if (t == 0) {
        int sx = bi / 9 - 4;
        int sy = bi % 9 - 4;
        best[b * 2]     = sx;
        best[b * 2 + 1] = sy;
        outTail[b * 2]     = (float)sx;
        outTail[b * 2 + 1] = (float)sy;
    }
}

// out[b,c,i,j] = in-bounds(i-sx, j-sy) ? x[b,c,i-sx,j-sy] : 0
__global__ __launch_bounds__(256) void k_apply(const float* __restrict__ x,
                                               const int* __restrict__ best,
                                               float* __restrict__ out) {
    int idx = blockIdx.x * blockDim.x + threadIdx.x;   // one float4 per thread
    int j0     = (idx % (WW / 4)) * 4;
    int rowIdx = idx / (WW / 4);                        // row across b,c,i
    int i  = rowIdx % HH;
    int bc = rowIdx / HH;
    int b  = bc / CC;
    int sx = best[b * 2];
    int sy = best[b * 2 + 1];
    int is = i - sx;
    float4 v = make_float4(0.f, 0.f, 0.f, 0.f);
    if (is >= 0 && is < HH) {
        const float* src = x + (size_t)bc * IMG + is * WW;
        float* vv = (float*)&v;
#pragma unroll
        for (int k = 0; k < 4; ++k) {
            int js = j0 + k - sy;
            if (js >= 0 && js < WW) vv[k] = src[js];
        }
    }
    *(float4*)(out + (size_t)bc * IMG + i * WW + j0) = v;
}

extern "C" void kernel_launch(void* const* d_in, const int* in_sizes, int n_in,
                              void* d_out, int out_size, void* d_ws, size_t ws_size,
                              hipStream_t stream) {
    const float* xref = (const float*)d_in[0];
    const float* x    = (const float*)d_in[1];
    float* out = (float*)d_out;

    double* sims = (double*)d_ws;
    int*    best = (int*)((char*)d_ws + 4096);

    k_init<<<1, 512, 0, stream>>>(sims);

    int simBlocks = BB * CC * (HH / ROWS);   // 768
    k_sims<<<simBlocks, 256, 0, stream>>>(xref, x, sims);

    k_argmax<<<BB, 64, 0, stream>>>(sims, best, out + (size_t)BB * CHW);

    int applyBlocks = (BB * CHW / 4) / 256;  // 3072
    k_apply<<<applyBlocks, 256, 0, stream>>>(x, best, out);
}

// Round 2
// 120.167 us; speedup vs baseline: 3.9509x; 3.9509x over previous
//
#include <hip/hip_runtime.h>

#define BB 4
#define CC 3
#define HH 512
#define WW 512
#define NS 81              // 9 x 9 shifts
#define IMG (HH * WW)
#define CHW (CC * IMG)
#define RSTRIP 8           // rows per block in k_sims

// ws layout: double sims[BB*NS] at byte 0; int best[BB*2] at byte 4096.

__global__ void k_init(double* __restrict__ sims) {
    int i = threadIdx.x;
    if (i < BB * NS) sims[i] = 0.0;
}

// sim(b,sx,sy) = sum over c,i,j (both (i,j) and (i+sx,j+sy) in bounds) of
//               x[b,c,i,j] * x_ref[b,c,i+sx,j+sy]
// One wave per row (64 lanes x 8 floats = 512 cols). 81 fp32 accumulators
// per lane, 16-float ref window in registers -> 72 FMAs per 6 float4 loads.
__global__ __launch_bounds__(256, 3) void k_sims(const float* __restrict__ xref,
                                                 const float* __restrict__ x,
                                                 double* __restrict__ sims) {
    int bid = blockIdx.x;
    int r0  = (bid & 63) * RSTRIP;       // 64 blocks per image
    int bc  = bid >> 6;                  // 0 .. B*C-1
    int b   = bc / CC;
    const float* xp = x    + (size_t)bc * IMG;
    const float* rp = xref + (size_t)bc * IMG;
    int tid  = threadIdx.x;
    int lane = tid & 63;
    int wave = tid >> 6;
    int j0   = lane << 3;                // 8 floats per lane

    float acc[NS];
#pragma unroll
    for (int s = 0; s < NS; ++s) acc[s] = 0.f;

    for (int p = 0; p < RSTRIP / 4; ++p) {
        int ip = r0 + p * 4 + wave;      // this wave's x row
        const float* xrow = xp + ip * WW + j0;
        float x8[8];
        *(float4*)(x8)     = *(const float4*)(xrow);
        *(float4*)(x8 + 4) = *(const float4*)(xrow + 4);

#pragma unroll
        for (int sxi = 0; sxi < 9; ++sxi) {
            int ii = ip + sxi - 4;       // ref row (wave-uniform test)
            if ((unsigned)ii >= HH) continue;
            const float* rrow = rp + ii * WW + j0;
            float w[16];                 // ref cols [j0-4, j0+12)
            if (j0 >= 4) *(float4*)(w) = *(const float4*)(rrow - 4);
            else { w[0] = w[1] = w[2] = w[3] = 0.f; }
            *(float4*)(w + 4) = *(const float4*)(rrow);
            *(float4*)(w + 8) = *(const float4*)(rrow + 4);
            if (j0 + 12 <= WW) *(float4*)(w + 12) = *(const float4*)(rrow + 8);
            else { w[12] = w[13] = w[14] = w[15] = 0.f; }
#pragma unroll
            for (int syi = 0; syi < 9; ++syi)
#pragma unroll
                for (int k = 0; k < 8; ++k)
                    acc[sxi * 9 + syi] += x8[k] * w[k + syi];
        }
    }

    // wave reduce (fp32), block combine in LDS, one fp64 atomic per slot
    __shared__ float part[4][NS];
#pragma unroll
    for (int s = 0; s < NS; ++s) {
        float v = acc[s];
        for (int off = 32; off; off >>= 1) v += __shfl_down(v, off, 64);
        if (lane == 0) part[wave][s] = v;
    }
    __syncthreads();
    if (tid < NS) {
        double tot = (double)part[0][tid] + (double)part[1][tid]
                   + (double)part[2][tid] + (double)part[3][tid];
        atomicAdd(&sims[b * NS + tid], tot);
    }
}

// One block (64 threads) per batch: argmax with first-index tie-break.
__global__ void k_argmax(const double* __restrict__ sims,
                         int* __restrict__ best,
                         float* __restrict__ outTail) {
    int b = blockIdx.x;
    int t = threadIdx.x;        // 0..63
    double bv = -1.0e300;
    int bi = NS;                // sentinel larger than any real index
    for (int s = t; s < NS; s += 64) {
        double v = sims[b * NS + s];
        if (v > bv || (v == bv && s < bi)) { bv = v; bi = s; }
    }
    for (int off = 32; off; off >>= 1) {
        double ov = __shfl_down(bv, off, 64);
        int    oi = __shfl_down(bi, off, 64);
        if (ov > bv || (ov == bv && oi < bi)) { bv = ov; bi = oi; }
    }
    if (t == 0) {
        int sx = bi / 9 - 4;
        int sy = bi % 9 - 4;
        best[b * 2]     = sx;
        best[b * 2 + 1] = sy;
        outTail[b * 2]     = (float)sx;
        outTail[b * 2 + 1] = (float)sy;
    }
}

// out[b,c,i,j] = in-bounds(i-sx, j-sy) ? x[b,c,i-sx,j-sy] : 0
__global__ __launch_bounds__(256) void k_apply(const float* __restrict__ x,
                                               const int* __restrict__ best,
                                               float* __restrict__ out) {
    int idx = blockIdx.x * blockDim.x + threadIdx.x;   // one float4 per thread
    int j0     = (idx % (WW / 4)) * 4;
    int rowIdx = idx / (WW / 4);                        // row across b,c,i
    int i  = rowIdx % HH;
    int bc = rowIdx / HH;
    int b  = bc / CC;
    int sx = best[b * 2];
    int sy = best[b * 2 + 1];
    int is = i - sx;
    float4 v = make_float4(0.f, 0.f, 0.f, 0.f);
    if (is >= 0 && is < HH) {
        const float* src = x + (size_t)bc * IMG + is * WW;
        float* vv = (float*)&v;
#pragma unroll
        for (int k = 0; k < 4; ++k) {
            int js = j0 + k - sy;
            if (js >= 0 && js < WW) vv[k] = src[js];
        }
    }
    *(float4*)(out + (size_t)bc * IMG + i * WW + j0) = v;
}

extern "C" void kernel_launch(void* const* d_in, const int* in_sizes, int n_in,
                              void* d_out, int out_size, void* d_ws, size_t ws_size,
                              hipStream_t stream) {
    const float* xref = (const float*)d_in[0];
    const float* x    = (const float*)d_in[1];
    float* out = (float*)d_out;

    double* sims = (double*)d_ws;
    int*    best = (int*)((char*)d_ws + 4096);

    k_init<<<1, 512, 0, stream>>>(sims);

    int simBlocks = BB * CC * (HH / RSTRIP);   // 768
    k_sims<<<simBlocks, 256, 0, stream>>>(xref, x, sims);

    k_argmax<<<BB, 64, 0, stream>>>(sims, best, out + (size_t)BB * CHW);

    int applyBlocks = (BB * CHW / 4) / 256;    // 3072
    k_apply<<<applyBlocks, 256, 0, stream>>>(x, best, out);
}

// Round 3
// 113.908 us; speedup vs baseline: 4.1680x; 1.0550x over previous
//
#include <hip/hip_runtime.h>

#define BB 4
#define CC 3
#define HH 512
#define WW 512
#define NS 81              // 9 x 9 shifts
#define IMG (HH * WW)
#define CHW (CC * IMG)
#define STRIP 8            // rows per k_sims block
#define NSTRIP (HH / STRIP)        // 64
#define NSXG 3             // sx groups of 3
#define NBLK (BB * CC * NSTRIP * NSXG)   // 2304

// ws layout: float partials[NBLK][27] at byte 0 (249 KB); int best[BB*2] after.
#define BEST_OFF (NBLK * 27 * sizeof(float))

// sim(b,sx,sy) = sum over c,i,j (both (i,j) and (i+sx,j+sy) in bounds) of
//               x[b,c,i,j] * x_ref[b,c,i+sx,j+sy]
// One block = (bc, 8-row strip, 3 consecutive sx). 27 fp32 accumulators/lane,
// lane owns 8 consecutive x-pixels; 16-float ref window -> 72 FMAs / 4 loads.
__global__ __launch_bounds__(256, 6) void k_sims(const float* __restrict__ xref,
                                                 const float* __restrict__ x,
                                                 float* __restrict__ partials) {
    int bid  = blockIdx.x;
    int sxg  = bid % NSXG;
    int tmp  = bid / NSXG;
    int strip = tmp % NSTRIP;
    int bc   = tmp / NSTRIP;
    int r0   = strip * STRIP;
    const float* xp = x    + (size_t)bc * IMG;
    const float* rp = xref + (size_t)bc * IMG;
    int tid  = threadIdx.x;
    int lane = tid & 63;
    int wave = tid >> 6;
    int j0   = lane << 3;            // 8 floats per lane

    float acc[27];
#pragma unroll
    for (int s = 0; s < 27; ++s) acc[s] = 0.f;

#pragma unroll
    for (int r = 0; r < 2; ++r) {
        int ip = r0 + wave * 2 + r;          // this wave's x row
        const float* xrow = xp + ip * WW + j0;
        float x8[8];
        *(float4*)(x8)     = *(const float4*)(xrow);
        *(float4*)(x8 + 4) = *(const float4*)(xrow + 4);

#pragma unroll
        for (int sxl = 0; sxl < 3; ++sxl) {
            int ii = ip + sxg * 3 + sxl - 4;   // ref row (wave-uniform test)
            if ((unsigned)ii >= HH) continue;
            const float* rrow = rp + ii * WW + j0;
            float w[16];                       // ref cols [j0-4, j0+12)
            if (j0 >= 4) *(float4*)(w) = *(const float4*)(rrow - 4);   // 4B-aligned ok
            else { w[0] = w[1] = w[2] = w[3] = 0.f; }
            *(float4*)(w + 4) = *(const float4*)(rrow);
            *(float4*)(w + 8) = *(const float4*)(rrow + 4);
            if (j0 + 12 <= WW) *(float4*)(w + 12) = *(const float4*)(rrow + 8);
            else { w[12] = w[13] = w[14] = w[15] = 0.f; }
#pragma unroll
            for (int syi = 0; syi < 9; ++syi)
#pragma unroll
                for (int k = 0; k < 8; ++k)
                    acc[sxl * 9 + syi] += x8[k] * w[k + syi];
        }
    }

    // wave reduce (fp32), block combine in LDS, direct store (no atomics)
    __shared__ float part[4][27];
#pragma unroll
    for (int s = 0; s < 27; ++s) {
        float v = acc[s];
        for (int off = 32; off; off >>= 1) v += __shfl_down(v, off, 64);
        if (lane == 0) part[wave][s] = v;
    }
    __syncthreads();
    if (tid < 27)
        partials[bid * 27 + tid] = part[0][tid] + part[1][tid]
                                 + part[2][tid] + part[3][tid];
}

// One block (128 threads) per batch: fp64 sum of per-block partials, then
// argmax with first-index tie-break (strict > keeps lowest index).
__global__ void k_argmax(const float* __restrict__ partials,
                         int* __restrict__ best,
                         float* __restrict__ outTail) {
    int b = blockIdx.x;
    int t = threadIdx.x;
    __shared__ double vals[NS];
    if (t < NS) {
        int sxi = t / 9, syi = t % 9;
        int sxg = sxi / 3;
        int within = (sxi - sxg * 3) * 9 + syi;
        double acc = 0.0;
        for (int c = 0; c < CC; ++c)
            for (int st = 0; st < NSTRIP; ++st) {
                int pb = ((b * CC + c) * NSTRIP + st) * NSXG + sxg;
                acc += (double)partials[pb * 27 + within];
            }
        vals[t] = acc;
    }
    __syncthreads();
    if (t == 0) {
        double bv = vals[0];
        int bi = 0;
        for (int s = 1; s < NS; ++s)
            if (vals[s] > bv) { bv = vals[s]; bi = s; }
        int sx = bi / 9 - 4;
        int sy = bi % 9 - 4;
        best[b * 2]     = sx;
        best[b * 2 + 1] = sy;
        outTail[b * 2]     = (float)sx;
        outTail[b * 2 + 1] = (float)sy;
    }
}

// out[b,c,i,j] = in-bounds(i-sx, j-sy) ? x[b,c,i-sx,j-sy] : 0
// One block = 2 rows of one (b,c) image; fast path = unaligned float4 load.
__global__ __launch_bounds__(256) void k_apply(const float* __restrict__ x,
                                               const int* __restrict__ best,
                                               float* __restrict__ out) {
    int blk = blockIdx.x;
    int bc  = blk >> 8;                 // 256 blocks per image (512 rows / 2)
    int tid = threadIdx.x;
    int row = ((blk & 255) << 1) + (tid >> 7);
    int j0  = (tid & 127) << 2;
    int b   = bc / CC;                  // block-uniform -> scalar loads of best
    int sx  = best[b * 2];
    int sy  = best[b * 2 + 1];
    int is  = row - sx;
    float4 v = make_float4(0.f, 0.f, 0.f, 0.f);
    if ((unsigned)is < HH) {
        const float* src = x + (size_t)bc * IMG + is * WW;
        int js0 = j0 - sy;
        if (js0 >= 0 && js0 + 3 < WW) {
            v = *(const float4*)(src + js0);   // 4B-aligned dwordx4, exact (R2)
        } else {
            float* vv = (float*)&v;
#pragma unroll
            for (int k = 0; k < 4; ++k) {
                int js = js0 + k;
                if ((unsigned)js < WW) vv[k] = src[js];
            }
        }
    }
    *(float4*)(out + (size_t)bc * IMG + row * WW + j0) = v;
}

extern "C" void kernel_launch(void* const* d_in, const int* in_sizes, int n_in,
                              void* d_out, int out_size, void* d_ws, size_t ws_size,
                              hipStream_t stream) {
    const float* xref = (const float*)d_in[0];
    const float* x    = (const float*)d_in[1];
    float* out = (float*)d_out;

    float* partials = (float*)d_ws;
    int*   best     = (int*)((char*)d_ws + BEST_OFF);

    k_sims<<<NBLK, 256, 0, stream>>>(xref, x, partials);

    k_argmax<<<BB, 128, 0, stream>>>(partials, best, out + (size_t)BB * CHW);

    int applyBlocks = (BB * CC * HH) / 2;   // 3072
    k_apply<<<applyBlocks, 256, 0, stream>>>(x, best, out);
}